// Round 2
// baseline (393.953 us; speedup 1.0000x reference)
//
#include <hip/hip_runtime.h>

// r = 1 - cov(x,y)/sqrt(|var(x)*var(y)|) per row (cov identity for
// 0.5*(var(x+y)-var(x)-var(y))), then mean over 768 rows.
// Pass 1: 5 sufficient stats (Sx,Sy,Sxx,Syy,Sxy) per (row,chunk) block.
// Pass 2: single block combines chunks -> per-row r -> mean.
//
// R4: counters showed delivered BW pinned at 3.1 TB/s with VGPR=36 =>
// only ~2-3 float4 loads in flight per wave (20 VGPRs eaten by the 5 f4
// accumulators). Named registers alone don't stop the scheduler from
// interleaving consumption into the load batch. This version pins the
// boundary with __builtin_amdgcn_sched_barrier(0): all 32 float4 loads
// (both superbatches, 128 dest VGPRs) issue before ANY consumption.
// launch_bounds min-waves clamp removed so the allocator can take ~150
// VGPRs without spilling. 12 waves/CU x 32KB in flight = 40x the
// latency-hiding requirement at 6.3 TB/s.

#define ROWS 768          // 8*16*6
#define ROW_ELEMS 65536   // 256*256
#define BLOCK 256
#define SPLIT 4                         // chunks per row
#define NBLK (ROWS * SPLIT)             // 3072 partial blocks

typedef float f4 __attribute__((ext_vector_type(4)));

__global__ __launch_bounds__(BLOCK) void partial_kernel(const float* __restrict__ x,
                                                        const float* __restrict__ y,
                                                        float* __restrict__ part) {
    const int blk = blockIdx.x;          // row*SPLIT + chunk
    const size_t base = (size_t)blk * (ROW_ELEMS / SPLIT);
    const f4* __restrict__ x4 = (const f4*)(x + base);
    const f4* __restrict__ y4 = (const f4*)(y + base);
    const int tid = threadIdx.x;

    f4 vsx = {0.f, 0.f, 0.f, 0.f};
    f4 vsy = {0.f, 0.f, 0.f, 0.f};
    f4 vsxx = {0.f, 0.f, 0.f, 0.f};
    f4 vsyy = {0.f, 0.f, 0.f, 0.f};
    f4 vsxy = {0.f, 0.f, 0.f, 0.f};

    // 4096 f4 per chunk / 256 threads = 16 f4/thread, split as two
    // superbatches of (8 x-f4 + 8 y-f4). ALL 32 loads are issued before
    // any FMA: sched_barrier(0) fences forbid the scheduler from moving
    // consumption up into the load groups.
    const int i0 = tid;               // superbatch 0 base (f4 index)
    const int i1 = tid + BLOCK * 8;   // superbatch 1 base

    const f4 a0 = x4[i0 + 0 * BLOCK];
    const f4 a1 = x4[i0 + 1 * BLOCK];
    const f4 a2 = x4[i0 + 2 * BLOCK];
    const f4 a3 = x4[i0 + 3 * BLOCK];
    const f4 a4 = x4[i0 + 4 * BLOCK];
    const f4 a5 = x4[i0 + 5 * BLOCK];
    const f4 a6 = x4[i0 + 6 * BLOCK];
    const f4 a7 = x4[i0 + 7 * BLOCK];
    const f4 b0 = y4[i0 + 0 * BLOCK];
    const f4 b1 = y4[i0 + 1 * BLOCK];
    const f4 b2 = y4[i0 + 2 * BLOCK];
    const f4 b3 = y4[i0 + 3 * BLOCK];
    const f4 b4 = y4[i0 + 4 * BLOCK];
    const f4 b5 = y4[i0 + 5 * BLOCK];
    const f4 b6 = y4[i0 + 6 * BLOCK];
    const f4 b7 = y4[i0 + 7 * BLOCK];
    __builtin_amdgcn_sched_barrier(0);

    const f4 c0 = x4[i1 + 0 * BLOCK];
    const f4 c1 = x4[i1 + 1 * BLOCK];
    const f4 c2 = x4[i1 + 2 * BLOCK];
    const f4 c3 = x4[i1 + 3 * BLOCK];
    const f4 c4 = x4[i1 + 4 * BLOCK];
    const f4 c5 = x4[i1 + 5 * BLOCK];
    const f4 c6 = x4[i1 + 6 * BLOCK];
    const f4 c7 = x4[i1 + 7 * BLOCK];
    const f4 d0 = y4[i1 + 0 * BLOCK];
    const f4 d1 = y4[i1 + 1 * BLOCK];
    const f4 d2 = y4[i1 + 2 * BLOCK];
    const f4 d3 = y4[i1 + 3 * BLOCK];
    const f4 d4 = y4[i1 + 4 * BLOCK];
    const f4 d5 = y4[i1 + 5 * BLOCK];
    const f4 d6 = y4[i1 + 6 * BLOCK];
    const f4 d7 = y4[i1 + 7 * BLOCK];
    __builtin_amdgcn_sched_barrier(0);

    // Superbatch 0 consumption (same j=0..7 order as before)
    vsx += a0; vsy += b0; vsxx += a0 * a0; vsyy += b0 * b0; vsxy += a0 * b0;
    vsx += a1; vsy += b1; vsxx += a1 * a1; vsyy += b1 * b1; vsxy += a1 * b1;
    vsx += a2; vsy += b2; vsxx += a2 * a2; vsyy += b2 * b2; vsxy += a2 * b2;
    vsx += a3; vsy += b3; vsxx += a3 * a3; vsyy += b3 * b3; vsxy += a3 * b3;
    vsx += a4; vsy += b4; vsxx += a4 * a4; vsyy += b4 * b4; vsxy += a4 * b4;
    vsx += a5; vsy += b5; vsxx += a5 * a5; vsyy += b5 * b5; vsxy += a5 * b5;
    vsx += a6; vsy += b6; vsxx += a6 * a6; vsyy += b6 * b6; vsxy += a6 * b6;
    vsx += a7; vsy += b7; vsxx += a7 * a7; vsyy += b7 * b7; vsxy += a7 * b7;

    // Superbatch 1 consumption
    vsx += c0; vsy += d0; vsxx += c0 * c0; vsyy += d0 * d0; vsxy += c0 * d0;
    vsx += c1; vsy += d1; vsxx += c1 * c1; vsyy += d1 * d1; vsxy += c1 * d1;
    vsx += c2; vsy += d2; vsxx += c2 * c2; vsyy += d2 * d2; vsxy += c2 * d2;
    vsx += c3; vsy += d3; vsxx += c3 * c3; vsyy += d3 * d3; vsxy += c3 * d3;
    vsx += c4; vsy += d4; vsxx += c4 * c4; vsyy += d4 * d4; vsxy += c4 * d4;
    vsx += c5; vsy += d5; vsxx += c5 * c5; vsyy += d5 * d5; vsxy += c5 * d5;
    vsx += c6; vsy += d6; vsxx += c6 * c6; vsyy += d6 * d6; vsxy += c6 * d6;
    vsx += c7; vsy += d7; vsxx += c7 * c7; vsyy += d7 * d7; vsxy += c7 * d7;

    // horizontal reduce vector accumulators to scalars
    float sx  = vsx.x  + vsx.y  + vsx.z  + vsx.w;
    float sy  = vsy.x  + vsy.y  + vsy.z  + vsy.w;
    float sxx = vsxx.x + vsxx.y + vsxx.z + vsxx.w;
    float syy = vsyy.x + vsyy.y + vsyy.z + vsyy.w;
    float sxy = vsxy.x + vsxy.y + vsxy.z + vsxy.w;

    // 64-lane wave shuffle reduction
    #pragma unroll
    for (int off = 32; off > 0; off >>= 1) {
        sx  += __shfl_down(sx,  off);
        sy  += __shfl_down(sy,  off);
        sxx += __shfl_down(sxx, off);
        syy += __shfl_down(syy, off);
        sxy += __shfl_down(sxy, off);
    }

    __shared__ float sm[5][BLOCK / 64];
    const int wave = tid >> 6;
    const int lane = tid & 63;
    if (lane == 0) {
        sm[0][wave] = sx;  sm[1][wave] = sy;
        sm[2][wave] = sxx; sm[3][wave] = syy;
        sm[4][wave] = sxy;
    }
    __syncthreads();

    if (tid == 0) {
        float t0 = 0.f, t1 = 0.f, t2 = 0.f, t3 = 0.f, t4 = 0.f;
        #pragma unroll
        for (int w = 0; w < BLOCK / 64; ++w) {
            t0 += sm[0][w]; t1 += sm[1][w];
            t2 += sm[2][w]; t3 += sm[3][w];
            t4 += sm[4][w];
        }
        // struct-of-arrays for coalesced reads in pass 2
        part[0 * NBLK + blk] = t0;
        part[1 * NBLK + blk] = t1;
        part[2 * NBLK + blk] = t2;
        part[3 * NBLK + blk] = t3;
        part[4 * NBLK + blk] = t4;
    }
}

__global__ __launch_bounds__(BLOCK) void finalize_kernel(const float* __restrict__ part,
                                                         float* __restrict__ out) {
    float acc = 0.f;
    for (int row = threadIdx.x; row < ROWS; row += BLOCK) {
        float tsx = 0.f, tsy = 0.f, tsxx = 0.f, tsyy = 0.f, tsxy = 0.f;
        #pragma unroll
        for (int c = 0; c < SPLIT; ++c) {
            const int b = row * SPLIT + c;
            tsx  += part[0 * NBLK + b];
            tsy  += part[1 * NBLK + b];
            tsxx += part[2 * NBLK + b];
            tsyy += part[3 * NBLK + b];
            tsxy += part[4 * NBLK + b];
        }
        const float n = (float)ROW_ELEMS;
        const float inv_nm1 = 1.0f / (n - 1.0f);
        float vx  = (tsxx - tsx * tsx / n) * inv_nm1;
        float vy  = (tsyy - tsy * tsy / n) * inv_nm1;
        float cov = (tsxy - tsx * tsy / n) * inv_nm1;
        acc += 1.0f - cov / sqrtf(fabsf(vx * vy));
    }

    #pragma unroll
    for (int off = 32; off > 0; off >>= 1) acc += __shfl_down(acc, off);

    __shared__ float sm[BLOCK / 64];
    const int wave = threadIdx.x >> 6;
    const int lane = threadIdx.x & 63;
    if (lane == 0) sm[wave] = acc;
    __syncthreads();

    if (threadIdx.x == 0) {
        float t = 0.f;
        #pragma unroll
        for (int w = 0; w < BLOCK / 64; ++w) t += sm[w];
        out[0] = t / (float)ROWS;
    }
}

extern "C" void kernel_launch(void* const* d_in, const int* in_sizes, int n_in,
                              void* d_out, int out_size, void* d_ws, size_t ws_size,
                              hipStream_t stream) {
    const float* x = (const float*)d_in[0];
    const float* y = (const float*)d_in[1];
    float* part = (float*)d_ws;   // 5 * 3072 floats = 60 KB scratch
    float* out = (float*)d_out;

    partial_kernel<<<NBLK, BLOCK, 0, stream>>>(x, y, part);
    finalize_kernel<<<1, BLOCK, 0, stream>>>(part, out);
}